// Round 2
// baseline (279.942 us; speedup 1.0000x reference)
//
#include <hip/hip_runtime.h>
#include <hip/hip_bf16.h>
#include <cmath>

constexpr int D_MODEL = 1024;
constexpr int NHEAD   = 16;
constexpr int DH      = 64;
constexpr int BATCH   = 4;
constexpr int SEQ     = 2048;
constexpr int TOKENS  = BATCH * SEQ;          // 8192
constexpr float SCALE = 0.125f;               // 64^-0.5
// folded into q inside rope_bf16_kernel: q' = (SCALE*log2e) * rot(q)
constexpr float QSF   = 0.125f * 1.44269504088896340736f;

typedef __attribute__((ext_vector_type(8))) short bf16x8;
typedef __attribute__((ext_vector_type(4))) short short4v;
typedef __attribute__((ext_vector_type(4))) float f32x4;
typedef __attribute__((ext_vector_type(4))) unsigned u32x4;

__device__ inline short f2bf(float f) {
    union { float f; unsigned u; } v; v.f = f;
    unsigned r = v.u + 0x7FFFu + ((v.u >> 16) & 1u);
    return (short)(r >> 16);
}
__device__ inline float bf2f(short s) {
    union { float f; unsigned u; } v;
    v.u = ((unsigned)(unsigned short)s) << 16;
    return v.f;
}
__device__ inline void llds16(const void* g, void* l) {
    __builtin_amdgcn_global_load_lds(
        (const __attribute__((address_space(1))) unsigned*)g,
        (__attribute__((address_space(3))) unsigned*)l, 16, 0, 0);
}

// ---------------------------------------------------------------------------
// Merged f32 -> bf16 convert for x, Wqkv_w, Wo_w (one launch, 3 segments)
// ---------------------------------------------------------------------------
constexpr int N8_X    = TOKENS * 1024 / 8;    // 1048576
constexpr int N8_WQKV = 3072 * 1024 / 8;      //  393216
constexpr int N8_WO   = 1024 * 1024 / 8;      //  131072

__global__ __launch_bounds__(256) void cvt3_bf16_kernel(
    const float* __restrict__ sx, const float* __restrict__ sq,
    const float* __restrict__ so,
    short* __restrict__ dx, short* __restrict__ dq, short* __restrict__ dw)
{
    int i = blockIdx.x * blockDim.x + threadIdx.x;
    const float* src; short* dst; int off;
    if (i < N8_X)                  { src = sx; dst = dx;  off = i; }
    else if (i < N8_X + N8_WQKV)   { src = sq; dst = dq;  off = i - N8_X; }
    else                           { src = so; dst = dw;  off = i - N8_X - N8_WQKV; }
    const float4* s = (const float4*)src + (size_t)off * 2;
    float4 a = s[0], b = s[1];
    bf16x8 v;
    v[0] = f2bf(a.x); v[1] = f2bf(a.y); v[2] = f2bf(a.z); v[3] = f2bf(a.w);
    v[4] = f2bf(b.x); v[5] = f2bf(b.y); v[6] = f2bf(b.z); v[7] = f2bf(b.w);
    *(bf16x8*)(dst + (size_t)off * 8) = v;
}

// ---------------------------------------------------------------------------
// bf16 MFMA GEMM: C[M,N] = A[M,K] @ B[N,K]^T + bias[N] (unchanged from r3)
// ---------------------------------------------------------------------------
template<int OUT_BF16>
__global__ __launch_bounds__(256) void gemm_mfma_kernel(
    const short* __restrict__ A, const short* __restrict__ B,
    const float* __restrict__ bias, void* __restrict__ C,
    int M, int N, int K)
{
    __shared__ short As[128 * 64];
    __shared__ short Bs[128 * 64];
    const int tid  = threadIdx.x;
    const int w    = tid >> 6;
    const int lane = tid & 63;
    const int q16  = lane & 15;
    const int quad = lane >> 4;
    const int wm   = (w & 1) * 64;
    const int wn   = (w >> 1) * 64;
    const int bm   = blockIdx.x * 128;
    const int bn   = blockIdx.y * 128;

    const int srow = w * 32 + (lane >> 3);
    const int kcs  = lane & 7;

    f32x4 acc[4][4];
    #pragma unroll
    for (int i = 0; i < 4; i++)
        #pragma unroll
        for (int j = 0; j < 4; j++) acc[i][j] = (f32x4){0.f, 0.f, 0.f, 0.f};

    for (int k0 = 0; k0 < K; k0 += 64) {
        __syncthreads();
        #pragma unroll
        for (int i = 0; i < 4; i++) {
            int row = srow + i * 8;
            int kc  = kcs ^ (row & 7);
            const short* ga = A + (size_t)(bm + row) * K + k0 + kc * 8;
            const short* gb = B + (size_t)(bn + row) * K + k0 + kc * 8;
            short* la = &As[(w * 32 + i * 8) * 64];
            short* lb = &Bs[(w * 32 + i * 8) * 64];
            llds16(ga, la);
            llds16(gb, lb);
        }
        __syncthreads();
        #pragma unroll
        for (int ks = 0; ks < 2; ks++) {
            bf16x8 af[4], bfr[4];
            #pragma unroll
            for (int t = 0; t < 4; t++) {
                int ra = wm + t * 16 + q16;
                int ca = (ks * 4 + quad) ^ (ra & 7);
                af[t]  = *(const bf16x8*)&As[ra * 64 + ca * 8];
                int rb = wn + t * 16 + q16;
                int cb = (ks * 4 + quad) ^ (rb & 7);
                bfr[t] = *(const bf16x8*)&Bs[rb * 64 + cb * 8];
            }
            #pragma unroll
            for (int mb = 0; mb < 4; mb++)
                #pragma unroll
                for (int nb = 0; nb < 4; nb++)
                    acc[mb][nb] = __builtin_amdgcn_mfma_f32_16x16x32_bf16(
                        af[mb], bfr[nb], acc[mb][nb], 0, 0, 0);
        }
    }

    #pragma unroll
    for (int nb = 0; nb < 4; nb++) {
        const int cn = bn + wn + nb * 16 + q16;
        const float bv = bias[cn];
        #pragma unroll
        for (int mb = 0; mb < 4; mb++) {
            const int rm = bm + wm + mb * 16 + quad * 4;
            #pragma unroll
            for (int r = 0; r < 4; r++) {
                float v = acc[mb][nb][r] + bv;
                if (OUT_BF16)
                    ((short*)C)[(size_t)(rm + r) * N + cn] = f2bf(v);
                else
                    ((float*)C)[(size_t)(rm + r) * N + cn] = v;
            }
        }
    }
}

// ---------------------------------------------------------------------------
// In-place RoPE on bf16 qkv, scale folded into q (r5). r6: trig via HW
// builtins — freq = exp2(-i*log2(1e4)/32)/(2pi) (revolutions), v_fract +
// v_sin/v_cos. Angle error ~1e-4 rad << bf16 rounding of the operands.
// ---------------------------------------------------------------------------
__global__ __launch_bounds__(256) void rope_bf16_kernel(
    short* __restrict__ qkv, const int* __restrict__ p)
{
    int idx = blockIdx.x * blockDim.x + threadIdx.x;
    int i   = idx & 31;
    int h   = (idx >> 5) & 15;
    int tok = idx >> 9;
    if (tok >= TOKENS) return;
    // log2(10000)/32 = 0.415241012; 1/(2pi) = 0.15915494309
    float frev = __builtin_amdgcn_exp2f((float)i * -0.4152410118609203f)
                 * 0.15915494309189535f;
    float t = (float)p[tok] * frev;
    t -= floorf(t);
    float sn = __builtin_amdgcn_sinf(t);   // sin(2*pi*t)
    float c  = __builtin_amdgcn_cosf(t);
    short* base = qkv + (size_t)tok * 3072 + h * 64 + i;
    float q1 = bf2f(base[0]),    q2 = bf2f(base[32]);
    base[0]    = f2bf(fmaf(q1, c,  q2 * sn) * QSF);   // scale folded into q
    base[32]   = f2bf(fmaf(q2, c, -q1 * sn) * QSF);
    float k1 = bf2f(base[1024]), k2 = bf2f(base[1056]);
    base[1024] = f2bf(fmaf(k1, c,  k2 * sn));
    base[1056] = f2bf(fmaf(k2, c, -k1 * sn));
}

// ---------------------------------------------------------------------------
// MFMA flash attention v6. S^T = K @ Q^T (verified layouts m89/m91/m120).
// r8 changes vs r7 (occupancy attack — chain QK->exp->cvt->permlane->PV is
// latency-exposed at 2 waves/SIMD):
//  - 128 q/block (2 qb per wave, was 4), grid 1024 = 4 blocks/CU
//    = 4 waves/SIMD. Per-wave state halves (qf/o/lsum), VGPR fits the
//    128-reg cap that 4 waves/SIMD needs; __launch_bounds__(256,4).
//  - bh = gid&63 unchanged: the 16 q-blocks of one (b,h) all land on one
//    XCD, so doubled block-level K/V re-reads stay L2-resident.
// Unchanged from r7: P never touches LDS (cvt_pk + permlane16_swap, Vs key
// axis pi-permuted); double-buffered K/V, one barrier/tile, no online max
// (bounded scores); bare v_exp_f32; LDS 32KB/block.
// ---------------------------------------------------------------------------
__global__ __launch_bounds__(256, 4) void attn_mfma_kernel(
    const short* __restrict__ qkv, short* __restrict__ out)
{
    __shared__ short Ks[2][64 * 64];   // [buf][key-row][dim-chunk swz]
    __shared__ short Vs[2][64 * 64];   // [buf][dim-row][key-chunk swz, pi-permuted]

    const int tid  = threadIdx.x;
    const int w    = tid >> 6;
    const int lane = tid & 63;
    const int q16  = lane & 15;
    const int quad = lane >> 4;
    const int gid  = blockIdx.x;
    const int bh   = gid & 63;       // XCD co-location for K/V reuse
    const int qblk = gid >> 6;       // 0..15
    const int b    = bh >> 4;
    const int h    = bh & 15;
    const int qtok0 = qblk * 128 + w * 32;

    // Q fragments (pre-scaled by rope kernel)
    bf16x8 qf[2][2];
    #pragma unroll
    for (int qb = 0; qb < 2; qb++) {
        const short* Qrow =
            qkv + (size_t)(b * SEQ + qtok0 + qb * 16 + q16) * 3072 + h * 64;
        qf[qb][0] = *(const bf16x8*)(Qrow + quad * 8);
        qf[qb][1] = *(const bf16x8*)(Qrow + 32 + quad * 8);
    }

    f32x4 o[2][4];
    #pragma unroll
    for (int qb = 0; qb < 2; qb++)
        #pragma unroll
        for (int md = 0; md < 4; md++) o[qb][md] = (f32x4){0.f, 0.f, 0.f, 0.f};
    float lsum[2] = {0.f, 0.f};

    const short* Kg = qkv + (size_t)b * SEQ * 3072 + 1024 + h * 64;
    const short* Vg = Kg + 1024;

    // staging constants
    const int krow = w * 16 + (lane >> 3);          // K row this lane fetches
    const int kc   = (lane & 7) ^ (krow & 7);       // swizzled source chunk
    const int vkey = (tid & 31) * 2;                // V: 2 keys per thread
    const int vdb  = (tid >> 5) * 8;                // V: 8 dims per thread
    // pi-permuted logical chunk for this thread's key pair (vkey even ->
    // vkey,vkey+1 share a chunk, at positions vkey&7, (vkey&7)+1)
    const int vL   = ((vkey >> 5) << 2) | (((vkey >> 3) & 1) << 1) | ((vkey >> 4) & 1);

    // V perm-pack + swizzled write: row = vdb+j (row&7 == j), chunk' = vL^j
    auto vwrite = [&](int buf, const uint4& a, const uint4& bb) {
        #pragma unroll
        for (int j = 0; j < 8; j++) {
            unsigned lo = (j & 1) ? 0x07060302u : 0x05040100u;
            unsigned sa = (&a.x)[j >> 1], sb = (&bb.x)[j >> 1];
            *(unsigned*)&Vs[buf][(vdb + j) * 64 + ((vL ^ j) << 3) + (vkey & 7)] =
                __builtin_amdgcn_perm(sb, sa, lo);
        }
    };

    // ---- prologue: stage tile 0 into buf 0 ----
    {
        llds16(Kg + (size_t)krow * 3072 + kc * 8, &Ks[0][(w * 16) * 64]);
        llds16(Kg + (size_t)(krow + 8) * 3072 + kc * 8, &Ks[0][(w * 16 + 8) * 64]);
        const short* vsrc = Vg + (size_t)vkey * 3072 + vdb;
        uint4 a  = *(const uint4*)vsrc;
        uint4 bb = *(const uint4*)(vsrc + 3072);
        vwrite(0, a, bb);
    }
    __syncthreads();

    int cur = 0;
    for (int t = 0; t < SEQ / 64; t++) {
        // prefetch tile t+1 into buf cur^1
        uint4 pva, pvb;
        const bool pf = (t < SEQ / 64 - 1);
        if (pf) {
            const int ktn = (t + 1) * 64;
            llds16(Kg + (size_t)(ktn + krow) * 3072 + kc * 8,
                   &Ks[cur ^ 1][(w * 16) * 64]);
            llds16(Kg + (size_t)(ktn + krow + 8) * 3072 + kc * 8,
                   &Ks[cur ^ 1][(w * 16 + 8) * 64]);
            const short* vsrc = Vg + (size_t)(ktn + vkey) * 3072 + vdb;
            pva = *(const uint4*)vsrc;
            pvb = *(const uint4*)(vsrc + 3072);
        }

        // fragment loads from buf cur (af/av share the address expression)
        bf16x8 af[4][2], av[4][2];
        #pragma unroll
        for (int mb = 0; mb < 4; mb++) {
            #pragma unroll
            for (int ks = 0; ks < 2; ks++) {
                int c = (((ks * 4 + quad) ^ (q16 & 7))) * 8;
                af[mb][ks] = *(const bf16x8*)&Ks[cur][(mb * 16 + q16) * 64 + c];
                av[mb][ks] = *(const bf16x8*)&Vs[cur][(mb * 16 + q16) * 64 + c];
            }
        }

        #pragma unroll
        for (int qb = 0; qb < 2; qb++) {
            // scores S^T (A = K, B = Q^T); scale already inside q
            f32x4 sc[4];
            #pragma unroll
            for (int mb = 0; mb < 4; mb++) {
                f32x4 c = {0.f, 0.f, 0.f, 0.f};
                c = __builtin_amdgcn_mfma_f32_16x16x32_bf16(af[mb][0], qf[qb][0], c, 0, 0, 0);
                c = __builtin_amdgcn_mfma_f32_16x16x32_bf16(af[mb][1], qf[qb][1], c, 0, 0, 0);
                sc[mb] = c;
            }
            float ltile = 0.f;
            unsigned da[4], db[4];
            // exp + pack mb 0,1 (keys for PV ks=0)
            #pragma unroll
            for (int mb = 0; mb < 2; mb++) {
                float p0 = __builtin_amdgcn_exp2f(sc[mb][0]);
                float p1 = __builtin_amdgcn_exp2f(sc[mb][1]);
                float p2 = __builtin_amdgcn_exp2f(sc[mb][2]);
                float p3 = __builtin_amdgcn_exp2f(sc[mb][3]);
                ltile += (p0 + p1) + (p2 + p3);
                asm("v_cvt_pk_bf16_f32 %0, %1, %2" : "=v"(da[mb]) : "v"(p0), "v"(p1));
                asm("v_cvt_pk_bf16_f32 %0, %1, %2" : "=v"(db[mb]) : "v"(p2), "v"(p3));
            }
            // in-register quad-pair exchange: vdst rows 1,3 <-> vsrc rows 0,2
            asm("v_permlane16_swap_b32 %0, %1" : "+v"(da[0]), "+v"(da[1]));
            asm("v_permlane16_swap_b32 %0, %1" : "+v"(db[0]), "+v"(db[1]));
            union { u32x4 u; bf16x8 v; } pb0;
            pb0.u = (u32x4){da[0], db[0], da[1], db[1]};
            // exp + pack mb 2,3 (overlaps PV ks=0 below)
            #pragma unroll
            for (int mb = 2; mb < 4; mb++) {
                float p0 = __builtin_amdgcn_exp2f(sc[mb][0]);
                float p1 = __builtin_amdgcn_exp2f(sc[mb][1]);
                float p2 = __builtin_amdgcn_exp2f(sc[mb][2]);
                float p3 = __builtin_amdgcn_exp2f(sc[mb][3]);
                ltile += (p0 + p1) + (p2 + p3);
                asm("v_cvt_pk_bf16_f32 %0, %1, %2" : "=v"(da[mb]) : "v"(p0), "v"(p1));
                asm("v_cvt_pk_bf16_f32 %0, %1, %2" : "=v"(db[mb]) : "v"(p2), "v"(p3));
            }
            // PV ks=0
            #pragma unroll
            for (int md = 0; md < 4; md++)
                o[qb][md] = __builtin_amdgcn_mfma_f32_16x16x32_bf16(
                    av[md][0], pb0.v, o[qb][md], 0, 0, 0);
            asm("v_permlane16_swap_b32 %0, %1" : "+v"(da[2]), "+v"(da[3]));
            asm("v_permlane16_swap_b32 %0, %1" : "+v"(db[2]), "+v"(db[3]));
            union { u32x4 u; bf16x8 v; } pb1;
            pb1.u = (u32x4){da[2], db[2], da[3], db[3]};
            // PV ks=1
            #pragma unroll
            for (int md = 0; md < 4; md++)
                o[qb][md] = __builtin_amdgcn_mfma_f32_16x16x32_bf16(
                    av[md][1], pb1.v, o[qb][md], 0, 0, 0);
            lsum[qb] += ltile;
        }

        // write prefetched V into buf cur^1 after compute
        if (pf) vwrite(cur ^ 1, pva, pvb);
        __syncthreads();
        cur ^= 1;
    }

    // epilogue: cross-quad l reduction, normalize, store bf16
    #pragma unroll
    for (int qb = 0; qb < 2; qb++) {
        float l = lsum[qb];
        l += __shfl_xor(l, 16);
        l += __shfl_xor(l, 32);
        float inv = 1.f / l;
        short* orow = out + (size_t)(b * SEQ + qtok0 + qb * 16 + q16) * 1024
                      + h * 64 + quad * 4;
        #pragma unroll
        for (int md = 0; md < 4; md++) {
            short4v t;
            t[0] = f2bf(o[qb][md][0] * inv);
            t[1] = f2bf(o[qb][md][1] * inv);
            t[2] = f2bf(o[qb][md][2] * inv);
            t[3] = f2bf(o[qb][md][3] * inv);
            *(short4v*)(orow + md * 16) = t;
        }
    }
}

// ---------------------------------------------------------------------------
extern "C" void kernel_launch(void* const* d_in, const int* in_sizes, int n_in,
                              void* d_out, int out_size, void* d_ws, size_t ws_size,
                              hipStream_t stream)
{
    (void)in_sizes; (void)n_in; (void)out_size; (void)ws_size;
    const float* x      = (const float*)d_in[0];
    const int*   p      = (const int*)  d_in[1];
    const float* Wqkv_w = (const float*)d_in[2];
    const float* Wqkv_b = (const float*)d_in[3];
    const float* Wo_w   = (const float*)d_in[4];
    const float* Wo_b   = (const float*)d_in[5];
    float* out = (float*)d_out;

    short* xb     = (short*)d_ws;                         // 16 MiB
    short* wqkvb  = xb + (size_t)TOKENS * 1024;           // 6 MiB
    short* wob    = wqkvb + (size_t)3072 * 1024;          // 2 MiB
    short* qkvb   = wob + (size_t)1024 * 1024;            // 48 MiB
    short* attnob = qkvb + (size_t)TOKENS * 3072;         // 16 MiB

    dim3 blk(256);

    cvt3_bf16_kernel<<<dim3((N8_X + N8_WQKV + N8_WO) / 256), blk, 0, stream>>>(
        x, Wqkv_w, Wo_w, xb, wqkvb, wob);

    gemm_mfma_kernel<1><<<dim3(TOKENS / 128, 3072 / 128), blk, 0, stream>>>(
        xb, wqkvb, Wqkv_b, qkvb, TOKENS, 3072, 1024);

    rope_bf16_kernel<<<dim3(TOKENS * NHEAD * 32 / 256), blk, 0, stream>>>(qkvb, p);

    attn_mfma_kernel<<<dim3(1024), blk, 0, stream>>>(qkvb, attnob);

    gemm_mfma_kernel<0><<<dim3(TOKENS / 128, 1024 / 128), blk, 0, stream>>>(
        attnob, wob, Wo_b, out, TOKENS, 1024, 1024);
}

// Round 3
// 275.860 us; speedup vs baseline: 1.0148x; 1.0148x over previous
//
#include <hip/hip_runtime.h>
#include <hip/hip_bf16.h>
#include <cmath>

constexpr int D_MODEL = 1024;
constexpr int NHEAD   = 16;
constexpr int DH      = 64;
constexpr int BATCH   = 4;
constexpr int SEQ     = 2048;
constexpr int TOKENS  = BATCH * SEQ;          // 8192
constexpr float SCALE = 0.125f;               // 64^-0.5
// folded into q inside rope_bf16_kernel: q' = (SCALE*log2e) * rot(q)
constexpr float QSF   = 0.125f * 1.44269504088896340736f;

typedef __attribute__((ext_vector_type(8))) short bf16x8;
typedef __attribute__((ext_vector_type(4))) short short4v;
typedef __attribute__((ext_vector_type(4))) float f32x4;
typedef __attribute__((ext_vector_type(4))) unsigned u32x4;

__device__ inline short f2bf(float f) {
    union { float f; unsigned u; } v; v.f = f;
    unsigned r = v.u + 0x7FFFu + ((v.u >> 16) & 1u);
    return (short)(r >> 16);
}
__device__ inline float bf2f(short s) {
    union { float f; unsigned u; } v;
    v.u = ((unsigned)(unsigned short)s) << 16;
    return v.f;
}
__device__ inline void llds16(const void* g, void* l) {
    __builtin_amdgcn_global_load_lds(
        (const __attribute__((address_space(1))) unsigned*)g,
        (__attribute__((address_space(3))) unsigned*)l, 16, 0, 0);
}

// ---------------------------------------------------------------------------
// Merged f32 -> bf16 convert for x, Wqkv_w, Wo_w (one launch, 3 segments)
// ---------------------------------------------------------------------------
constexpr int N8_X    = TOKENS * 1024 / 8;    // 1048576
constexpr int N8_WQKV = 3072 * 1024 / 8;      //  393216
constexpr int N8_WO   = 1024 * 1024 / 8;      //  131072

__global__ __launch_bounds__(256) void cvt3_bf16_kernel(
    const float* __restrict__ sx, const float* __restrict__ sq,
    const float* __restrict__ so,
    short* __restrict__ dx, short* __restrict__ dq, short* __restrict__ dw)
{
    int i = blockIdx.x * blockDim.x + threadIdx.x;
    const float* src; short* dst; int off;
    if (i < N8_X)                  { src = sx; dst = dx;  off = i; }
    else if (i < N8_X + N8_WQKV)   { src = sq; dst = dq;  off = i - N8_X; }
    else                           { src = so; dst = dw;  off = i - N8_X - N8_WQKV; }
    const float4* s = (const float4*)src + (size_t)off * 2;
    float4 a = s[0], b = s[1];
    bf16x8 v;
    v[0] = f2bf(a.x); v[1] = f2bf(a.y); v[2] = f2bf(a.z); v[3] = f2bf(a.w);
    v[4] = f2bf(b.x); v[5] = f2bf(b.y); v[6] = f2bf(b.z); v[7] = f2bf(b.w);
    *(bf16x8*)(dst + (size_t)off * 8) = v;
}

// ---------------------------------------------------------------------------
// bf16 MFMA GEMM: C[M,N] = A[M,K] @ B[N,K]^T + bias[N] (unchanged from r3)
// ---------------------------------------------------------------------------
template<int OUT_BF16>
__global__ __launch_bounds__(256) void gemm_mfma_kernel(
    const short* __restrict__ A, const short* __restrict__ B,
    const float* __restrict__ bias, void* __restrict__ C,
    int M, int N, int K)
{
    __shared__ short As[128 * 64];
    __shared__ short Bs[128 * 64];
    const int tid  = threadIdx.x;
    const int w    = tid >> 6;
    const int lane = tid & 63;
    const int q16  = lane & 15;
    const int quad = lane >> 4;
    const int wm   = (w & 1) * 64;
    const int wn   = (w >> 1) * 64;
    const int bm   = blockIdx.x * 128;
    const int bn   = blockIdx.y * 128;

    const int srow = w * 32 + (lane >> 3);
    const int kcs  = lane & 7;

    f32x4 acc[4][4];
    #pragma unroll
    for (int i = 0; i < 4; i++)
        #pragma unroll
        for (int j = 0; j < 4; j++) acc[i][j] = (f32x4){0.f, 0.f, 0.f, 0.f};

    for (int k0 = 0; k0 < K; k0 += 64) {
        __syncthreads();
        #pragma unroll
        for (int i = 0; i < 4; i++) {
            int row = srow + i * 8;
            int kc  = kcs ^ (row & 7);
            const short* ga = A + (size_t)(bm + row) * K + k0 + kc * 8;
            const short* gb = B + (size_t)(bn + row) * K + k0 + kc * 8;
            short* la = &As[(w * 32 + i * 8) * 64];
            short* lb = &Bs[(w * 32 + i * 8) * 64];
            llds16(ga, la);
            llds16(gb, lb);
        }
        __syncthreads();
        #pragma unroll
        for (int ks = 0; ks < 2; ks++) {
            bf16x8 af[4], bfr[4];
            #pragma unroll
            for (int t = 0; t < 4; t++) {
                int ra = wm + t * 16 + q16;
                int ca = (ks * 4 + quad) ^ (ra & 7);
                af[t]  = *(const bf16x8*)&As[ra * 64 + ca * 8];
                int rb = wn + t * 16 + q16;
                int cb = (ks * 4 + quad) ^ (rb & 7);
                bfr[t] = *(const bf16x8*)&Bs[rb * 64 + cb * 8];
            }
            #pragma unroll
            for (int mb = 0; mb < 4; mb++)
                #pragma unroll
                for (int nb = 0; nb < 4; nb++)
                    acc[mb][nb] = __builtin_amdgcn_mfma_f32_16x16x32_bf16(
                        af[mb], bfr[nb], acc[mb][nb], 0, 0, 0);
        }
    }

    #pragma unroll
    for (int nb = 0; nb < 4; nb++) {
        const int cn = bn + wn + nb * 16 + q16;
        const float bv = bias[cn];
        #pragma unroll
        for (int mb = 0; mb < 4; mb++) {
            const int rm = bm + wm + mb * 16 + quad * 4;
            #pragma unroll
            for (int r = 0; r < 4; r++) {
                float v = acc[mb][nb][r] + bv;
                if (OUT_BF16)
                    ((short*)C)[(size_t)(rm + r) * N + cn] = f2bf(v);
                else
                    ((float*)C)[(size_t)(rm + r) * N + cn] = v;
            }
        }
    }
}

// ---------------------------------------------------------------------------
// In-place RoPE on bf16 qkv, scale folded into q (r5). r6: trig via HW
// builtins — freq = exp2(-i*log2(1e4)/32)/(2pi) (revolutions), v_fract +
// v_sin/v_cos. Angle error ~1e-4 rad << bf16 rounding of the operands.
// ---------------------------------------------------------------------------
__global__ __launch_bounds__(256) void rope_bf16_kernel(
    short* __restrict__ qkv, const int* __restrict__ p)
{
    int idx = blockIdx.x * blockDim.x + threadIdx.x;
    int i   = idx & 31;
    int h   = (idx >> 5) & 15;
    int tok = idx >> 9;
    if (tok >= TOKENS) return;
    // log2(10000)/32 = 0.415241012; 1/(2pi) = 0.15915494309
    float frev = __builtin_amdgcn_exp2f((float)i * -0.4152410118609203f)
                 * 0.15915494309189535f;
    float t = (float)p[tok] * frev;
    t -= floorf(t);
    float sn = __builtin_amdgcn_sinf(t);   // sin(2*pi*t)
    float c  = __builtin_amdgcn_cosf(t);
    short* base = qkv + (size_t)tok * 3072 + h * 64 + i;
    float q1 = bf2f(base[0]),    q2 = bf2f(base[32]);
    base[0]    = f2bf(fmaf(q1, c,  q2 * sn) * QSF);   // scale folded into q
    base[32]   = f2bf(fmaf(q2, c, -q1 * sn) * QSF);
    float k1 = bf2f(base[1024]), k2 = bf2f(base[1056]);
    base[1024] = f2bf(fmaf(k1, c,  k2 * sn));
    base[1056] = f2bf(fmaf(k2, c, -k1 * sn));
}

// ---------------------------------------------------------------------------
// MFMA flash attention v7. S^T = K @ Q^T (verified layouts m89/m91/m120).
// r9 changes vs r7 (ILP attack; r8's occupancy-doubling was flat because it
// also doubled per-useful-work overhead — reverted):
//  - qb software pipeline (T15-analog): QK MFMAs for qb+1 are issued BEFORE
//    the softmax VALU of qb, so the matrix pipe processes the next score
//    tile while the VALU does exp/cvt/permlane of the current. sc is a
//    2-deep ping-pong (sc[qb&1], statically indexed under full unroll).
//  - s_setprio(1) around MFMA clusters (T5): the 2 co-resident blocks/CU
//    drift out of phase, giving the arbiter something to do.
// Unchanged from r7: 4 qb/wave, grid 512 (2 blocks/CU), P never touches LDS
// (cvt_pk + permlane16_swap, Vs key axis pi-permuted); double-buffered K/V,
// one barrier/tile, no online max (bounded scores); LDS 32KB/block.
// ---------------------------------------------------------------------------
__global__ __launch_bounds__(256, 2) void attn_mfma_kernel(
    const short* __restrict__ qkv, short* __restrict__ out)
{
    __shared__ short Ks[2][64 * 64];   // [buf][key-row][dim-chunk swz]
    __shared__ short Vs[2][64 * 64];   // [buf][dim-row][key-chunk swz, pi-permuted]

    const int tid  = threadIdx.x;
    const int w    = tid >> 6;
    const int lane = tid & 63;
    const int q16  = lane & 15;
    const int quad = lane >> 4;
    const int gid  = blockIdx.x;
    const int bh   = gid & 63;       // XCD co-location for K/V reuse
    const int qblk = gid >> 6;       // 0..7
    const int b    = bh >> 4;
    const int h    = bh & 15;
    const int qtok0 = qblk * 256 + w * 64;

    // Q fragments (pre-scaled by rope kernel)
    bf16x8 qf[4][2];
    #pragma unroll
    for (int qb = 0; qb < 4; qb++) {
        const short* Qrow =
            qkv + (size_t)(b * SEQ + qtok0 + qb * 16 + q16) * 3072 + h * 64;
        qf[qb][0] = *(const bf16x8*)(Qrow + quad * 8);
        qf[qb][1] = *(const bf16x8*)(Qrow + 32 + quad * 8);
    }

    f32x4 o[4][4];
    #pragma unroll
    for (int qb = 0; qb < 4; qb++)
        #pragma unroll
        for (int md = 0; md < 4; md++) o[qb][md] = (f32x4){0.f, 0.f, 0.f, 0.f};
    float lsum[4] = {0.f, 0.f, 0.f, 0.f};

    const short* Kg = qkv + (size_t)b * SEQ * 3072 + 1024 + h * 64;
    const short* Vg = Kg + 1024;

    // staging constants
    const int krow = w * 16 + (lane >> 3);          // K row this lane fetches
    const int kc   = (lane & 7) ^ (krow & 7);       // swizzled source chunk
    const int vkey = (tid & 31) * 2;                // V: 2 keys per thread
    const int vdb  = (tid >> 5) * 8;                // V: 8 dims per thread
    // pi-permuted logical chunk for this thread's key pair (vkey even ->
    // vkey,vkey+1 share a chunk, at positions vkey&7, (vkey&7)+1)
    const int vL   = ((vkey >> 5) << 2) | (((vkey >> 3) & 1) << 1) | ((vkey >> 4) & 1);

    // V perm-pack + swizzled write: row = vdb+j (row&7 == j), chunk' = vL^j
    auto vwrite = [&](int buf, const uint4& a, const uint4& bb) {
        #pragma unroll
        for (int j = 0; j < 8; j++) {
            unsigned lo = (j & 1) ? 0x07060302u : 0x05040100u;
            unsigned sa = (&a.x)[j >> 1], sb = (&bb.x)[j >> 1];
            *(unsigned*)&Vs[buf][(vdb + j) * 64 + ((vL ^ j) << 3) + (vkey & 7)] =
                __builtin_amdgcn_perm(sb, sa, lo);
        }
    };

    // ---- prologue: stage tile 0 into buf 0 ----
    {
        llds16(Kg + (size_t)krow * 3072 + kc * 8, &Ks[0][(w * 16) * 64]);
        llds16(Kg + (size_t)(krow + 8) * 3072 + kc * 8, &Ks[0][(w * 16 + 8) * 64]);
        const short* vsrc = Vg + (size_t)vkey * 3072 + vdb;
        uint4 a  = *(const uint4*)vsrc;
        uint4 bb = *(const uint4*)(vsrc + 3072);
        vwrite(0, a, bb);
    }
    __syncthreads();

    int cur = 0;
    for (int t = 0; t < SEQ / 64; t++) {
        // prefetch tile t+1 into buf cur^1
        uint4 pva, pvb;
        const bool pf = (t < SEQ / 64 - 1);
        if (pf) {
            const int ktn = (t + 1) * 64;
            llds16(Kg + (size_t)(ktn + krow) * 3072 + kc * 8,
                   &Ks[cur ^ 1][(w * 16) * 64]);
            llds16(Kg + (size_t)(ktn + krow + 8) * 3072 + kc * 8,
                   &Ks[cur ^ 1][(w * 16 + 8) * 64]);
            const short* vsrc = Vg + (size_t)(ktn + vkey) * 3072 + vdb;
            pva = *(const uint4*)vsrc;
            pvb = *(const uint4*)(vsrc + 3072);
        }

        // fragment loads from buf cur (af/av share the address expression)
        bf16x8 af[4][2], av[4][2];
        #pragma unroll
        for (int mb = 0; mb < 4; mb++) {
            #pragma unroll
            for (int ks = 0; ks < 2; ks++) {
                int c = (((ks * 4 + quad) ^ (q16 & 7))) * 8;
                af[mb][ks] = *(const bf16x8*)&Ks[cur][(mb * 16 + q16) * 64 + c];
                av[mb][ks] = *(const bf16x8*)&Vs[cur][(mb * 16 + q16) * 64 + c];
            }
        }

        // qb software pipeline: sc ping-pong, QK(qb+1) issued before the
        // softmax VALU of qb so MFMA and VALU pipes overlap.
        f32x4 sc[2][4];
        __builtin_amdgcn_s_setprio(1);
        #pragma unroll
        for (int mb = 0; mb < 4; mb++) {
            f32x4 c = {0.f, 0.f, 0.f, 0.f};
            c = __builtin_amdgcn_mfma_f32_16x16x32_bf16(af[mb][0], qf[0][0], c, 0, 0, 0);
            c = __builtin_amdgcn_mfma_f32_16x16x32_bf16(af[mb][1], qf[0][1], c, 0, 0, 0);
            sc[0][mb] = c;
        }
        __builtin_amdgcn_s_setprio(0);

        #pragma unroll
        for (int qb = 0; qb < 4; qb++) {
            f32x4* scc = sc[qb & 1];
            f32x4* scn = sc[(qb & 1) ^ 1];
            // next qb's QK first — matrix pipe fills while VALU runs below
            if (qb < 3) {
                __builtin_amdgcn_s_setprio(1);
                #pragma unroll
                for (int mb = 0; mb < 4; mb++) {
                    f32x4 c = {0.f, 0.f, 0.f, 0.f};
                    c = __builtin_amdgcn_mfma_f32_16x16x32_bf16(af[mb][0], qf[qb + 1][0], c, 0, 0, 0);
                    c = __builtin_amdgcn_mfma_f32_16x16x32_bf16(af[mb][1], qf[qb + 1][1], c, 0, 0, 0);
                    scn[mb] = c;
                }
                __builtin_amdgcn_s_setprio(0);
            }
            float ltile = 0.f;
            unsigned da[4], db[4];
            // exp + pack mb 0,1 (keys for PV ks=0)
            #pragma unroll
            for (int mb = 0; mb < 2; mb++) {
                float p0 = __builtin_amdgcn_exp2f(scc[mb][0]);
                float p1 = __builtin_amdgcn_exp2f(scc[mb][1]);
                float p2 = __builtin_amdgcn_exp2f(scc[mb][2]);
                float p3 = __builtin_amdgcn_exp2f(scc[mb][3]);
                ltile += (p0 + p1) + (p2 + p3);
                asm("v_cvt_pk_bf16_f32 %0, %1, %2" : "=v"(da[mb]) : "v"(p0), "v"(p1));
                asm("v_cvt_pk_bf16_f32 %0, %1, %2" : "=v"(db[mb]) : "v"(p2), "v"(p3));
            }
            // in-register quad-pair exchange: vdst rows 1,3 <-> vsrc rows 0,2
            asm("v_permlane16_swap_b32 %0, %1" : "+v"(da[0]), "+v"(da[1]));
            asm("v_permlane16_swap_b32 %0, %1" : "+v"(db[0]), "+v"(db[1]));
            union { u32x4 u; bf16x8 v; } pb0;
            pb0.u = (u32x4){da[0], db[0], da[1], db[1]};
            // exp + pack mb 2,3 (overlaps PV ks=0 below)
            #pragma unroll
            for (int mb = 2; mb < 4; mb++) {
                float p0 = __builtin_amdgcn_exp2f(scc[mb][0]);
                float p1 = __builtin_amdgcn_exp2f(scc[mb][1]);
                float p2 = __builtin_amdgcn_exp2f(scc[mb][2]);
                float p3 = __builtin_amdgcn_exp2f(scc[mb][3]);
                ltile += (p0 + p1) + (p2 + p3);
                asm("v_cvt_pk_bf16_f32 %0, %1, %2" : "=v"(da[mb]) : "v"(p0), "v"(p1));
                asm("v_cvt_pk_bf16_f32 %0, %1, %2" : "=v"(db[mb]) : "v"(p2), "v"(p3));
            }
            // PV ks=0
            __builtin_amdgcn_s_setprio(1);
            #pragma unroll
            for (int md = 0; md < 4; md++)
                o[qb][md] = __builtin_amdgcn_mfma_f32_16x16x32_bf16(
                    av[md][0], pb0.v, o[qb][md], 0, 0, 0);
            __builtin_amdgcn_s_setprio(0);
            asm("v_permlane16_swap_b32 %0, %1" : "+v"(da[2]), "+v"(da[3]));
            asm("v_permlane16_swap_b32 %0, %1" : "+v"(db[2]), "+v"(db[3]));
            union { u32x4 u; bf16x8 v; } pb1;
            pb1.u = (u32x4){da[2], db[2], da[3], db[3]};
            // PV ks=1
            __builtin_amdgcn_s_setprio(1);
            #pragma unroll
            for (int md = 0; md < 4; md++)
                o[qb][md] = __builtin_amdgcn_mfma_f32_16x16x32_bf16(
                    av[md][1], pb1.v, o[qb][md], 0, 0, 0);
            __builtin_amdgcn_s_setprio(0);
            lsum[qb] += ltile;
        }

        // write prefetched V into buf cur^1 after compute
        if (pf) vwrite(cur ^ 1, pva, pvb);
        __syncthreads();
        cur ^= 1;
    }

    // epilogue: cross-quad l reduction, normalize, store bf16
    #pragma unroll
    for (int qb = 0; qb < 4; qb++) {
        float l = lsum[qb];
        l += __shfl_xor(l, 16);
        l += __shfl_xor(l, 32);
        float inv = 1.f / l;
        short* orow = out + (size_t)(b * SEQ + qtok0 + qb * 16 + q16) * 1024
                      + h * 64 + quad * 4;
        #pragma unroll
        for (int md = 0; md < 4; md++) {
            short4v t;
            t[0] = f2bf(o[qb][md][0] * inv);
            t[1] = f2bf(o[qb][md][1] * inv);
            t[2] = f2bf(o[qb][md][2] * inv);
            t[3] = f2bf(o[qb][md][3] * inv);
            *(short4v*)(orow + md * 16) = t;
        }
    }
}

// ---------------------------------------------------------------------------
extern "C" void kernel_launch(void* const* d_in, const int* in_sizes, int n_in,
                              void* d_out, int out_size, void* d_ws, size_t ws_size,
                              hipStream_t stream)
{
    (void)in_sizes; (void)n_in; (void)out_size; (void)ws_size;
    const float* x      = (const float*)d_in[0];
    const int*   p      = (const int*)  d_in[1];
    const float* Wqkv_w = (const float*)d_in[2];
    const float* Wqkv_b = (const float*)d_in[3];
    const float* Wo_w   = (const float*)d_in[4];
    const float* Wo_b   = (const float*)d_in[5];
    float* out = (float*)d_out;

    short* xb     = (short*)d_ws;                         // 16 MiB
    short* wqkvb  = xb + (size_t)TOKENS * 1024;           // 6 MiB
    short* wob    = wqkvb + (size_t)3072 * 1024;          // 2 MiB
    short* qkvb   = wob + (size_t)1024 * 1024;            // 48 MiB
    short* attnob = qkvb + (size_t)TOKENS * 3072;         // 16 MiB

    dim3 blk(256);

    cvt3_bf16_kernel<<<dim3((N8_X + N8_WQKV + N8_WO) / 256), blk, 0, stream>>>(
        x, Wqkv_w, Wo_w, xb, wqkvb, wob);

    gemm_mfma_kernel<1><<<dim3(TOKENS / 128, 3072 / 128), blk, 0, stream>>>(
        xb, wqkvb, Wqkv_b, qkvb, TOKENS, 3072, 1024);

    rope_bf16_kernel<<<dim3(TOKENS * NHEAD * 32 / 256), blk, 0, stream>>>(qkvb, p);

    attn_mfma_kernel<<<dim3(512), blk, 0, stream>>>(qkvb, attnob);

    gemm_mfma_kernel<0><<<dim3(TOKENS / 128, 1024 / 128), blk, 0, stream>>>(
        attnob, wob, Wo_b, out, TOKENS, 1024, 1024);
}

// Round 4
// 261.479 us; speedup vs baseline: 1.0706x; 1.0550x over previous
//
#include <hip/hip_runtime.h>
#include <hip/hip_bf16.h>
#include <cmath>

constexpr int D_MODEL = 1024;
constexpr int NHEAD   = 16;
constexpr int DH      = 64;
constexpr int BATCH   = 4;
constexpr int SEQ     = 2048;
constexpr int TOKENS  = BATCH * SEQ;          // 8192
constexpr float SCALE = 0.125f;               // 64^-0.5
// folded into q inside the QKV-GEMM rope epilogue: q' = (SCALE*log2e) * rot(q)
constexpr float QSF   = 0.125f * 1.44269504088896340736f;

typedef __attribute__((ext_vector_type(8))) short bf16x8;
typedef __attribute__((ext_vector_type(4))) short short4v;
typedef __attribute__((ext_vector_type(4))) float f32x4;
typedef __attribute__((ext_vector_type(4))) unsigned u32x4;

__device__ inline short f2bf(float f) {
    union { float f; unsigned u; } v; v.f = f;
    unsigned r = v.u + 0x7FFFu + ((v.u >> 16) & 1u);
    return (short)(r >> 16);
}
__device__ inline float bf2f(short s) {
    union { float f; unsigned u; } v;
    v.u = ((unsigned)(unsigned short)s) << 16;
    return v.f;
}
__device__ inline void llds16(const void* g, void* l) {
    __builtin_amdgcn_global_load_lds(
        (const __attribute__((address_space(1))) unsigned*)g,
        (__attribute__((address_space(3))) unsigned*)l, 16, 0, 0);
}

// ---------------------------------------------------------------------------
// Merged f32 -> bf16 convert for x, Wqkv_w, Wo_w (one launch, 3 segments)
// ---------------------------------------------------------------------------
constexpr int N8_X    = TOKENS * 1024 / 8;    // 1048576
constexpr int N8_WQKV = 3072 * 1024 / 8;      //  393216
constexpr int N8_WO   = 1024 * 1024 / 8;      //  131072

__global__ __launch_bounds__(256) void cvt3_bf16_kernel(
    const float* __restrict__ sx, const float* __restrict__ sq,
    const float* __restrict__ so,
    short* __restrict__ dx, short* __restrict__ dq, short* __restrict__ dw)
{
    int i = blockIdx.x * blockDim.x + threadIdx.x;
    const float* src; short* dst; int off;
    if (i < N8_X)                  { src = sx; dst = dx;  off = i; }
    else if (i < N8_X + N8_WQKV)   { src = sq; dst = dq;  off = i - N8_X; }
    else                           { src = so; dst = dw;  off = i - N8_X - N8_WQKV; }
    const float4* s = (const float4*)src + (size_t)off * 2;
    float4 a = s[0], b = s[1];
    bf16x8 v;
    v[0] = f2bf(a.x); v[1] = f2bf(a.y); v[2] = f2bf(a.z); v[3] = f2bf(a.w);
    v[4] = f2bf(b.x); v[5] = f2bf(b.y); v[6] = f2bf(b.z); v[7] = f2bf(b.w);
    *(bf16x8*)(dst + (size_t)off * 8) = v;
}

// ---------------------------------------------------------------------------
// bf16 MFMA GEMM: C[M,N] = A[M,K] @ B[N,K]^T + bias[N].
// r10: ROPE template param — for the QKV GEMM, RoPE is applied IN-REGISTER
// on the f32 accumulators before the bf16 store. Each wave's 64-col window
// (wn) is exactly one head (segment boundaries are 128-aligned), and the
// rotate pair (i, i+32) is (nb, nb+2) in the same wave. q additionally gets
// QSF folded in. Deletes the separate rope kernel + its 64MB qkv RMW.
// Trig identical to the old rope kernel: frev = exp2(-i*log2(1e4)/32)/(2pi),
// fract, v_sin/v_cos (revolutions).
// ---------------------------------------------------------------------------
template<int OUT_BF16, int ROPE>
__global__ __launch_bounds__(256) void gemm_mfma_kernel(
    const short* __restrict__ A, const short* __restrict__ B,
    const float* __restrict__ bias, void* __restrict__ C,
    const int* __restrict__ p, int M, int N, int K)
{
    __shared__ short As[128 * 64];
    __shared__ short Bs[128 * 64];
    const int tid  = threadIdx.x;
    const int w    = tid >> 6;
    const int lane = tid & 63;
    const int q16  = lane & 15;
    const int quad = lane >> 4;
    const int wm   = (w & 1) * 64;
    const int wn   = (w >> 1) * 64;
    const int bm   = blockIdx.x * 128;
    const int bn   = blockIdx.y * 128;

    const int srow = w * 32 + (lane >> 3);
    const int kcs  = lane & 7;

    f32x4 acc[4][4];
    #pragma unroll
    for (int i = 0; i < 4; i++)
        #pragma unroll
        for (int j = 0; j < 4; j++) acc[i][j] = (f32x4){0.f, 0.f, 0.f, 0.f};

    for (int k0 = 0; k0 < K; k0 += 64) {
        __syncthreads();
        #pragma unroll
        for (int i = 0; i < 4; i++) {
            int row = srow + i * 8;
            int kc  = kcs ^ (row & 7);
            const short* ga = A + (size_t)(bm + row) * K + k0 + kc * 8;
            const short* gb = B + (size_t)(bn + row) * K + k0 + kc * 8;
            short* la = &As[(w * 32 + i * 8) * 64];
            short* lb = &Bs[(w * 32 + i * 8) * 64];
            llds16(ga, la);
            llds16(gb, lb);
        }
        __syncthreads();
        #pragma unroll
        for (int ks = 0; ks < 2; ks++) {
            bf16x8 af[4], bfr[4];
            #pragma unroll
            for (int t = 0; t < 4; t++) {
                int ra = wm + t * 16 + q16;
                int ca = (ks * 4 + quad) ^ (ra & 7);
                af[t]  = *(const bf16x8*)&As[ra * 64 + ca * 8];
                int rb = wn + t * 16 + q16;
                int cb = (ks * 4 + quad) ^ (rb & 7);
                bfr[t] = *(const bf16x8*)&Bs[rb * 64 + cb * 8];
            }
            #pragma unroll
            for (int mb = 0; mb < 4; mb++)
                #pragma unroll
                for (int nb = 0; nb < 4; nb++)
                    acc[mb][nb] = __builtin_amdgcn_mfma_f32_16x16x32_bf16(
                        af[mb], bfr[nb], acc[mb][nb], 0, 0, 0);
        }
    }

    if (ROPE && (bn + wn) < 2 * D_MODEL) {
        // q or k head: rotate pairs (nb, nb+2) = dims (i, i+32), i = nb*16+q16
        const float sf = (bn + wn) < D_MODEL ? QSF : 1.0f;
        // positions for this lane's 16 rows (same for all nb)
        float posv[4][4];
        #pragma unroll
        for (int mb = 0; mb < 4; mb++) {
            const int rm = bm + wm + mb * 16 + quad * 4;
            #pragma unroll
            for (int r = 0; r < 4; r++) posv[mb][r] = (float)p[rm + r];
        }
        #pragma unroll
        for (int nb = 0; nb < 2; nb++) {
            const int i   = nb * 16 + q16;
            const int cn0 = bn + wn + i;
            const int cn1 = cn0 + 32;
            const float b0 = bias[cn0], b1 = bias[cn1];
            // identical expression to the old rope kernel (bit-matched trig)
            const float fr = __builtin_amdgcn_exp2f((float)i * -0.4152410118609203f)
                             * 0.15915494309189535f;
            #pragma unroll
            for (int mb = 0; mb < 4; mb++) {
                const int rm = bm + wm + mb * 16 + quad * 4;
                #pragma unroll
                for (int r = 0; r < 4; r++) {
                    float t = posv[mb][r] * fr;
                    t -= floorf(t);
                    float sn = __builtin_amdgcn_sinf(t);
                    float c  = __builtin_amdgcn_cosf(t);
                    float v0 = acc[mb][nb][r]     + b0;
                    float v1 = acc[mb][nb + 2][r] + b1;
                    ((short*)C)[(size_t)(rm + r) * N + cn0] =
                        f2bf(fmaf(v0, c,  v1 * sn) * sf);
                    ((short*)C)[(size_t)(rm + r) * N + cn1] =
                        f2bf(fmaf(v1, c, -v0 * sn) * sf);
                }
            }
        }
        return;
    }

    #pragma unroll
    for (int nb = 0; nb < 4; nb++) {
        const int cn = bn + wn + nb * 16 + q16;
        const float bv = bias[cn];
        #pragma unroll
        for (int mb = 0; mb < 4; mb++) {
            const int rm = bm + wm + mb * 16 + quad * 4;
            #pragma unroll
            for (int r = 0; r < 4; r++) {
                float v = acc[mb][nb][r] + bv;
                if (OUT_BF16)
                    ((short*)C)[(size_t)(rm + r) * N + cn] = f2bf(v);
                else
                    ((float*)C)[(size_t)(rm + r) * N + cn] = v;
            }
        }
    }
}

// ---------------------------------------------------------------------------
// MFMA flash attention v5 (r7 exact — best measured 87.4us; r8 occupancy and
// r9 qb-pipeline variants were both flat-to-negative, reverted).
// S^T = K @ Q^T (verified layouts m89/m91/m120). P never touches LDS: the
// quad-group key redistribution is done in-register — Vs key axis is stored
// PERMUTED (pi(ks,quad,j) = 16*(2ks+(quad&1)) + 8*(quad>>1) + j), making the
// exchange exactly v_permlane16_swap_b32 (vdst rows 1,3 <-> vsrc rows 0,2).
// Double-buffered K/V, one barrier/tile, no online max (bounded scores);
// 64 q/wave; scale pre-folded in q; bare v_exp_f32; bh = gid&63 L2 swizzle.
// LDS 32KB/block -> 2 blocks/CU (grid 512 = 2/CU exactly).
// ---------------------------------------------------------------------------
__global__ __launch_bounds__(256, 2) void attn_mfma_kernel(
    const short* __restrict__ qkv, short* __restrict__ out)
{
    __shared__ short Ks[2][64 * 64];   // [buf][key-row][dim-chunk swz]
    __shared__ short Vs[2][64 * 64];   // [buf][dim-row][key-chunk swz, pi-permuted]

    const int tid  = threadIdx.x;
    const int w    = tid >> 6;
    const int lane = tid & 63;
    const int q16  = lane & 15;
    const int quad = lane >> 4;
    const int gid  = blockIdx.x;
    const int bh   = gid & 63;       // XCD co-location for K/V reuse
    const int qblk = gid >> 6;       // 0..7
    const int b    = bh >> 4;
    const int h    = bh & 15;
    const int qtok0 = qblk * 256 + w * 64;

    // Q fragments (pre-scaled by the QKV-GEMM rope epilogue)
    bf16x8 qf[4][2];
    #pragma unroll
    for (int qb = 0; qb < 4; qb++) {
        const short* Qrow =
            qkv + (size_t)(b * SEQ + qtok0 + qb * 16 + q16) * 3072 + h * 64;
        qf[qb][0] = *(const bf16x8*)(Qrow + quad * 8);
        qf[qb][1] = *(const bf16x8*)(Qrow + 32 + quad * 8);
    }

    f32x4 o[4][4];
    #pragma unroll
    for (int qb = 0; qb < 4; qb++)
        #pragma unroll
        for (int md = 0; md < 4; md++) o[qb][md] = (f32x4){0.f, 0.f, 0.f, 0.f};
    float lsum[4] = {0.f, 0.f, 0.f, 0.f};

    const short* Kg = qkv + (size_t)b * SEQ * 3072 + 1024 + h * 64;
    const short* Vg = Kg + 1024;

    // staging constants
    const int krow = w * 16 + (lane >> 3);          // K row this lane fetches
    const int kc   = (lane & 7) ^ (krow & 7);       // swizzled source chunk
    const int vkey = (tid & 31) * 2;                // V: 2 keys per thread
    const int vdb  = (tid >> 5) * 8;                // V: 8 dims per thread
    // pi-permuted logical chunk for this thread's key pair (vkey even ->
    // vkey,vkey+1 share a chunk, at positions vkey&7, (vkey&7)+1)
    const int vL   = ((vkey >> 5) << 2) | (((vkey >> 3) & 1) << 1) | ((vkey >> 4) & 1);

    // V perm-pack + swizzled write: row = vdb+j (row&7 == j), chunk' = vL^j
    auto vwrite = [&](int buf, const uint4& a, const uint4& bb) {
        #pragma unroll
        for (int j = 0; j < 8; j++) {
            unsigned lo = (j & 1) ? 0x07060302u : 0x05040100u;
            unsigned sa = (&a.x)[j >> 1], sb = (&bb.x)[j >> 1];
            *(unsigned*)&Vs[buf][(vdb + j) * 64 + ((vL ^ j) << 3) + (vkey & 7)] =
                __builtin_amdgcn_perm(sb, sa, lo);
        }
    };

    // ---- prologue: stage tile 0 into buf 0 ----
    {
        llds16(Kg + (size_t)krow * 3072 + kc * 8, &Ks[0][(w * 16) * 64]);
        llds16(Kg + (size_t)(krow + 8) * 3072 + kc * 8, &Ks[0][(w * 16 + 8) * 64]);
        const short* vsrc = Vg + (size_t)vkey * 3072 + vdb;
        uint4 a  = *(const uint4*)vsrc;
        uint4 bb = *(const uint4*)(vsrc + 3072);
        vwrite(0, a, bb);
    }
    __syncthreads();

    int cur = 0;
    for (int t = 0; t < SEQ / 64; t++) {
        // prefetch tile t+1 into buf cur^1
        uint4 pva, pvb;
        const bool pf = (t < SEQ / 64 - 1);
        if (pf) {
            const int ktn = (t + 1) * 64;
            llds16(Kg + (size_t)(ktn + krow) * 3072 + kc * 8,
                   &Ks[cur ^ 1][(w * 16) * 64]);
            llds16(Kg + (size_t)(ktn + krow + 8) * 3072 + kc * 8,
                   &Ks[cur ^ 1][(w * 16 + 8) * 64]);
            const short* vsrc = Vg + (size_t)(ktn + vkey) * 3072 + vdb;
            pva = *(const uint4*)vsrc;
            pvb = *(const uint4*)(vsrc + 3072);
        }

        // fragment loads from buf cur (af/av share the address expression)
        bf16x8 af[4][2], av[4][2];
        #pragma unroll
        for (int mb = 0; mb < 4; mb++) {
            #pragma unroll
            for (int ks = 0; ks < 2; ks++) {
                int c = (((ks * 4 + quad) ^ (q16 & 7))) * 8;
                af[mb][ks] = *(const bf16x8*)&Ks[cur][(mb * 16 + q16) * 64 + c];
                av[mb][ks] = *(const bf16x8*)&Vs[cur][(mb * 16 + q16) * 64 + c];
            }
        }

        #pragma unroll
        for (int qb = 0; qb < 4; qb++) {
            // scores S^T (A = K, B = Q^T); scale already inside q
            f32x4 sc[4];
            #pragma unroll
            for (int mb = 0; mb < 4; mb++) {
                f32x4 c = {0.f, 0.f, 0.f, 0.f};
                c = __builtin_amdgcn_mfma_f32_16x16x32_bf16(af[mb][0], qf[qb][0], c, 0, 0, 0);
                c = __builtin_amdgcn_mfma_f32_16x16x32_bf16(af[mb][1], qf[qb][1], c, 0, 0, 0);
                sc[mb] = c;
            }
            float ltile = 0.f;
            unsigned da[4], db[4];
            // exp + pack mb 0,1 (keys for PV ks=0)
            #pragma unroll
            for (int mb = 0; mb < 2; mb++) {
                float p0 = __builtin_amdgcn_exp2f(sc[mb][0]);
                float p1 = __builtin_amdgcn_exp2f(sc[mb][1]);
                float p2 = __builtin_amdgcn_exp2f(sc[mb][2]);
                float p3 = __builtin_amdgcn_exp2f(sc[mb][3]);
                ltile += (p0 + p1) + (p2 + p3);
                asm("v_cvt_pk_bf16_f32 %0, %1, %2" : "=v"(da[mb]) : "v"(p0), "v"(p1));
                asm("v_cvt_pk_bf16_f32 %0, %1, %2" : "=v"(db[mb]) : "v"(p2), "v"(p3));
            }
            // in-register quad-pair exchange: vdst rows 1,3 <-> vsrc rows 0,2
            asm("v_permlane16_swap_b32 %0, %1" : "+v"(da[0]), "+v"(da[1]));
            asm("v_permlane16_swap_b32 %0, %1" : "+v"(db[0]), "+v"(db[1]));
            union { u32x4 u; bf16x8 v; } pb0;
            pb0.u = (u32x4){da[0], db[0], da[1], db[1]};
            // exp + pack mb 2,3 (overlaps PV ks=0 below)
            #pragma unroll
            for (int mb = 2; mb < 4; mb++) {
                float p0 = __builtin_amdgcn_exp2f(sc[mb][0]);
                float p1 = __builtin_amdgcn_exp2f(sc[mb][1]);
                float p2 = __builtin_amdgcn_exp2f(sc[mb][2]);
                float p3 = __builtin_amdgcn_exp2f(sc[mb][3]);
                ltile += (p0 + p1) + (p2 + p3);
                asm("v_cvt_pk_bf16_f32 %0, %1, %2" : "=v"(da[mb]) : "v"(p0), "v"(p1));
                asm("v_cvt_pk_bf16_f32 %0, %1, %2" : "=v"(db[mb]) : "v"(p2), "v"(p3));
            }
            // PV ks=0
            #pragma unroll
            for (int md = 0; md < 4; md++)
                o[qb][md] = __builtin_amdgcn_mfma_f32_16x16x32_bf16(
                    av[md][0], pb0.v, o[qb][md], 0, 0, 0);
            asm("v_permlane16_swap_b32 %0, %1" : "+v"(da[2]), "+v"(da[3]));
            asm("v_permlane16_swap_b32 %0, %1" : "+v"(db[2]), "+v"(db[3]));
            union { u32x4 u; bf16x8 v; } pb1;
            pb1.u = (u32x4){da[2], db[2], da[3], db[3]};
            // PV ks=1
            #pragma unroll
            for (int md = 0; md < 4; md++)
                o[qb][md] = __builtin_amdgcn_mfma_f32_16x16x32_bf16(
                    av[md][1], pb1.v, o[qb][md], 0, 0, 0);
            lsum[qb] += ltile;
        }

        // write prefetched V into buf cur^1 after compute
        if (pf) vwrite(cur ^ 1, pva, pvb);
        __syncthreads();
        cur ^= 1;
    }

    // epilogue: cross-quad l reduction, normalize, store bf16
    #pragma unroll
    for (int qb = 0; qb < 4; qb++) {
        float l = lsum[qb];
        l += __shfl_xor(l, 16);
        l += __shfl_xor(l, 32);
        float inv = 1.f / l;
        short* orow = out + (size_t)(b * SEQ + qtok0 + qb * 16 + q16) * 1024
                      + h * 64 + quad * 4;
        #pragma unroll
        for (int md = 0; md < 4; md++) {
            short4v t;
            t[0] = f2bf(o[qb][md][0] * inv);
            t[1] = f2bf(o[qb][md][1] * inv);
            t[2] = f2bf(o[qb][md][2] * inv);
            t[3] = f2bf(o[qb][md][3] * inv);
            *(short4v*)(orow + md * 16) = t;
        }
    }
}

// ---------------------------------------------------------------------------
extern "C" void kernel_launch(void* const* d_in, const int* in_sizes, int n_in,
                              void* d_out, int out_size, void* d_ws, size_t ws_size,
                              hipStream_t stream)
{
    (void)in_sizes; (void)n_in; (void)out_size; (void)ws_size;
    const float* x      = (const float*)d_in[0];
    const int*   p      = (const int*)  d_in[1];
    const float* Wqkv_w = (const float*)d_in[2];
    const float* Wqkv_b = (const float*)d_in[3];
    const float* Wo_w   = (const float*)d_in[4];
    const float* Wo_b   = (const float*)d_in[5];
    float* out = (float*)d_out;

    short* xb     = (short*)d_ws;                         // 16 MiB
    short* wqkvb  = xb + (size_t)TOKENS * 1024;           // 6 MiB
    short* wob    = wqkvb + (size_t)3072 * 1024;          // 2 MiB
    short* qkvb   = wob + (size_t)1024 * 1024;            // 48 MiB
    short* attnob = qkvb + (size_t)TOKENS * 3072;         // 16 MiB

    dim3 blk(256);

    cvt3_bf16_kernel<<<dim3((N8_X + N8_WQKV + N8_WO) / 256), blk, 0, stream>>>(
        x, Wqkv_w, Wo_w, xb, wqkvb, wob);

    gemm_mfma_kernel<1, 1><<<dim3(TOKENS / 128, 3072 / 128), blk, 0, stream>>>(
        xb, wqkvb, Wqkv_b, qkvb, p, TOKENS, 3072, 1024);

    attn_mfma_kernel<<<dim3(512), blk, 0, stream>>>(qkvb, attnob);

    gemm_mfma_kernel<0, 0><<<dim3(TOKENS / 128, 1024 / 128), blk, 0, stream>>>(
        attnob, wob, Wo_b, out, nullptr, TOKENS, 1024, 1024);
}